// Round 3
// baseline (865.289 us; speedup 1.0000x reference)
//
#include <hip/hip_runtime.h>

// SymplecticLayer: 2 leapfrog steps, force = grad of tanh-MLP Hamiltonian (8->128->128->1).
// Round 3: same algorithm as Round 2 (operand-swapped fp8 MFMA, bpermute layout
// transforms, register-resident state), but ALL locals are named scalars / f32x4s
// and the transform is a macro -- no address-taken arrays, so nothing escapes to
// scratch (Round 2 spilled ~1.4 KB/thread -> 3 GB HBM traffic).

typedef float f32x4 __attribute__((ext_vector_type(4)));

#define DT   0.01f
#define L2E2 2.8853901f   // 2*log2(e)

__device__ __forceinline__ int bperm(int idx, int v) {
    return __builtin_amdgcn_ds_bpermute(idx, v);
}
__device__ __forceinline__ int pack4(float a, float b, float c, float d) {
    int v = __builtin_amdgcn_cvt_pk_fp8_f32(a, b, 0, false);
    v = __builtin_amdgcn_cvt_pk_fp8_f32(c, d, v, true);
    return v;
}
__device__ __forceinline__ unsigned char to_fp8(float x) {
    return (unsigned char)(__builtin_amdgcn_cvt_pk_fp8_f32(x, x, 0, false) & 0xff);
}
__device__ __forceinline__ f32x4 mfma8(long long a, long long b, f32x4 c) {
    return __builtin_amdgcn_mfma_f32_16x16x32_fp8_fp8(a, b, c, 0, 0, 0);
}

// one B-frag dword-pair from two C-layout packed dwords (conflict-free crossbar)
#define XF(PKA, PKB, BF) {                                      \
    int la_ = bperm(idx_lo, (PKA));                             \
    int lb_ = bperm(idx_lo, (PKB));                             \
    int ha_ = bperm(idx_hi, (PKA));                             \
    int hb_ = bperm(idx_hi, (PKB));                             \
    int lo_ = sel ? la_ : lb_;                                  \
    int hi_ = sel ? ha_ : hb_;                                  \
    (BF) = (((long long)(unsigned)hi_) << 32) | (unsigned)lo_;  \
}
#define XFORM4() { XF(pk0,pk1,bf0); XF(pk2,pk3,bf1); XF(pk4,pk5,bf2); XF(pk6,pk7,bf3); }

#define TANHU(X, H, U) {                                        \
    float e_  = __builtin_amdgcn_exp2f((X) * L2E2);             \
    float rc_ = __builtin_amdgcn_rcpf(1.0f + e_);               \
    (H) = 1.0f - 2.0f * rc_;                                    \
    (U) = __builtin_fmaf(-(H), (H), 1.0f);                      \
}

// L1 fwd tile NT: h1 = tanh(z@W1+b1) -> PK (packed fp8), UV (1-h1^2)
#define L1FWD(NT, PK, UV) {                                                    \
    long long a_ = *(const long long*)(sW1A + (NT) * 512 + laneB);             \
    f32x4 acc_ = mfma8(a_, zB, (f32x4){0.f, 0.f, 0.f, 0.f});                   \
    float hA_, hB_, hC_, hD_;                                                  \
    TANHU(acc_[0], hA_, (UV)[0]); TANHU(acc_[1], hB_, (UV)[1]);                \
    TANHU(acc_[2], hC_, (UV)[2]); TANHU(acc_[3], hD_, (UV)[3]);                \
    (PK) = pack4(hA_, hB_, hC_, hD_);                                          \
}

// L2 fwd tile NT: d2' = 16*sech^2(h1@W2+b2) -> PK
#define L2FWD(NT, PK) {                                                        \
    f32x4 b2c_ = *(const f32x4*)(sB2 + (NT) * 16 + qd * 4);                    \
    f32x4 acc_ = {0.f, 0.f, 0.f, 0.f};                                         \
    acc_ = mfma8(*(const long long*)(sW2F + ((NT)*4+0)*512 + laneB), bf0, acc_); \
    acc_ = mfma8(*(const long long*)(sW2F + ((NT)*4+1)*512 + laneB), bf1, acc_); \
    acc_ = mfma8(*(const long long*)(sW2F + ((NT)*4+2)*512 + laneB), bf2, acc_); \
    acc_ = mfma8(*(const long long*)(sW2F + ((NT)*4+3)*512 + laneB), bf3, acc_); \
    float dA_, dB_, dC_, dD_;                                                  \
    D2OF(acc_[0], b2c_[0], dA_); D2OF(acc_[1], b2c_[1], dB_);                  \
    D2OF(acc_[2], b2c_[2], dC_); D2OF(acc_[3], b2c_[3], dD_);                  \
    (PK) = pack4(dA_, dB_, dC_, dD_);                                          \
}
#define D2OF(ACC, B2C, D) {                                                    \
    float arg_ = __builtin_fmaf((ACC), 0.36067376f, (B2C));                    \
    arg_ = fminf(arg_, 126.0f);                                                \
    float e_  = __builtin_amdgcn_exp2f(arg_);                                  \
    float rc_ = __builtin_amdgcn_rcpf(1.0f + e_);                              \
    (D) = 64.0f * (e_ * rc_) * rc_;                                            \
}

// L2 bwd tile NT: d1 = u .* (d2' @ w3W2^T) * (1/32) -> PK
#define L2BWD(NT, PK, UV) {                                                    \
    f32x4 acc_ = {0.f, 0.f, 0.f, 0.f};                                         \
    acc_ = mfma8(*(const long long*)(sW2R + ((NT)*4+0)*512 + laneB), bf0, acc_); \
    acc_ = mfma8(*(const long long*)(sW2R + ((NT)*4+1)*512 + laneB), bf1, acc_); \
    acc_ = mfma8(*(const long long*)(sW2R + ((NT)*4+2)*512 + laneB), bf2, acc_); \
    acc_ = mfma8(*(const long long*)(sW2R + ((NT)*4+3)*512 + laneB), bf3, acc_); \
    (PK) = pack4((acc_[0] * (UV)[0]) * 0.03125f, (acc_[1] * (UV)[1]) * 0.03125f, \
                 (acc_[2] * (UV)[2]) * 0.03125f, (acc_[3] * (UV)[3]) * 0.03125f); \
}

__global__ __launch_bounds__(256, 4) void hnn_kernel(
    const float* __restrict__ Z, const float* __restrict__ W1,
    const float* __restrict__ B1, const float* __restrict__ W2,
    const float* __restrict__ B2, const float* __restrict__ W3,
    float* __restrict__ OUT)
{
    // ---- LDS: 4096+16384+16384+2048+512 = 39,424 B -> 4 blocks/CU ----
    __shared__ __align__(16) unsigned char sW1A[4096];    // fwd A = W1^T (m=f, k=i; k=8 -> b1)
    __shared__ __align__(16) unsigned char sW2F[16384];   // fwd A = 8*W2^T (m=k2, k=j)
    __shared__ __align__(16) unsigned char sW2R[16384];   // bwd A = 128*w3(.)W2 (m=j, k=k2)
    __shared__ __align__(16) unsigned char sW1R[2048];    // bwd A = W1 (m=i pad16, k=f)
    __shared__ __align__(16) float sB2[128];              // b2 * 2log2e

    const int t = threadIdx.x, blk = blockIdx.x;

    for (int i = t; i < 1024; i += 256) ((int*)sW1A)[i] = 0;
    for (int i = t; i < 512;  i += 256) ((int*)sW1R)[i] = 0;
    __syncthreads();

    // W1 (8x128, row-major [i][f])
    for (int i = t; i < 1024; i += 256) {
        int i8 = i >> 7, f = i & 127;
        unsigned char q = to_fp8(W1[i]);
        sW1A[(f >> 4) * 512 + (f & 15) * 8 + i8] = q;
        sW1R[(f >> 5) * 512 + (i8 | (((f >> 3) & 3) << 4)) * 8 + (f & 7)] = q;
    }
    if (t < 128) {
        sW1A[(t >> 4) * 512 + ((t & 15) + 16) * 8] = to_fp8(B1[t]);  // bias row k=8
        sB2[t] = B2[t] * L2E2;
    }
    // W2 (128x128, row-major [j][k2])
    for (int i = t; i < 4096; i += 256) {
        f32x4 w  = ((const f32x4*)W2)[i];
        f32x4 w3 = *(const f32x4*)(W3 + ((i * 4) & 127));
        int j = (i * 4) >> 7, k0 = (i * 4) & 127;
        #pragma unroll
        for (int u = 0; u < 4; u++) {
            int k2 = k0 + u;
            sW2F[(((k2 >> 4) << 2) | (j >> 5)) * 512
                 + ((k2 & 15) | (((j >> 3) & 3) << 4)) * 8 + (j & 7)] = to_fp8(w[u] * 8.0f);
            sW2R[(((j >> 4) << 2) | (k2 >> 5)) * 512
                 + ((j & 15) | (((k2 >> 3) & 3) << 4)) * 8 + (k2 & 7)] = to_fp8(w[u] * w3[u] * 128.0f);
        }
    }
    __syncthreads();
    // No further barriers: everything below is wave-local.

    const int lane = t & 63, wv = t >> 6;
    const int c = lane & 15, qd = lane >> 4;
    const int laneB = lane * 8;
    const bool sel = qd < 2;
    const int idx_pt = (lane ^ 16) << 2;
    const int idx_lo = ((((2 * qd) & 3) << 4) | c) << 2;
    const int idx_hi = (((((2 * qd) | 1) & 3) << 4) | c) << 2;
    const int row = blk * 64 + wv * 16 + c;
    const float cp  = (qd == 0) ? (-0.5f * DT / 64.0f) : 0.0f;  // p -= 0.5*DT*dHdq (acc scale 64)
    const float cqb = (qd == 1) ? (DT / 64.0f) : 0.0f;          // q += DT*dHdp (even evs)

    // state: qd0/2 lanes hold p[c][0..3], qd1/3 lanes hold q[c][0..3]
    f32x4 st = *(const f32x4*)(Z + row * 8 + ((qd & 1) ? 0 : 4));

    f32x4 u0, u1, u2, u3, u4, u5, u6, u7;     // 1 - h1^2, C-layout
    int pk0, pk1, pk2, pk3, pk4, pk5, pk6, pk7;
    long long bf0, bf1, bf2, bf3;

    #pragma unroll 1
    for (int ev = 0; ev < 4; ev++) {
        // ---- build z B-frag: k=0..7 = (q,p), k=8 = 1.0 (bias row) ----
        int own = pack4(st[0], st[1], st[2], st[3]);
        int oth = bperm(idx_pt, own);
        int zlo = (qd == 0) ? oth : ((qd == 1) ? 0x38 : 0);   // 0x38 = e4m3(1.0)
        int zhi = (qd == 0) ? own : 0;
        long long zB = (((long long)(unsigned)zhi) << 32) | (unsigned)zlo;

        L1FWD(0, pk0, u0); L1FWD(1, pk1, u1); L1FWD(2, pk2, u2); L1FWD(3, pk3, u3);
        L1FWD(4, pk4, u4); L1FWD(5, pk5, u5); L1FWD(6, pk6, u6); L1FWD(7, pk7, u7);
        XFORM4();

        L2FWD(0, pk0); L2FWD(1, pk1); L2FWD(2, pk2); L2FWD(3, pk3);
        L2FWD(4, pk4); L2FWD(5, pk5); L2FWD(6, pk6); L2FWD(7, pk7);
        XFORM4();

        L2BWD(0, pk0, u0); L2BWD(1, pk1, u1); L2BWD(2, pk2, u2); L2BWD(3, pk3, u3);
        L2BWD(4, pk4, u4); L2BWD(5, pk5, u5); L2BWD(6, pk6, u6); L2BWD(7, pk7, u7);
        XFORM4();

        // ---- L1 bwd: g = d1 @ W1^T (m=0..3 dHdq -> qd0, m=4..7 dHdp -> qd1) ----
        f32x4 g = {0.f, 0.f, 0.f, 0.f};
        g = mfma8(*(const long long*)(sW1R + 0 * 512 + laneB), bf0, g);
        g = mfma8(*(const long long*)(sW1R + 1 * 512 + laneB), bf1, g);
        g = mfma8(*(const long long*)(sW1R + 2 * 512 + laneB), bf2, g);
        g = mfma8(*(const long long*)(sW1R + 3 * 512 + laneB), bf3, g);

        float coef = cp + ((ev & 1) ? 0.0f : cqb);
        st[0] = __builtin_fmaf(coef, g[0], st[0]);
        st[1] = __builtin_fmaf(coef, g[1], st[1]);
        st[2] = __builtin_fmaf(coef, g[2], st[2]);
        st[3] = __builtin_fmaf(coef, g[3], st[3]);
    }

    if (qd < 2) *(f32x4*)(OUT + row * 8 + ((qd & 1) ? 0 : 4)) = st;
}

extern "C" void kernel_launch(void* const* d_in, const int* in_sizes, int n_in,
                              void* d_out, int out_size, void* d_ws, size_t ws_size,
                              hipStream_t stream) {
    const float* Z  = (const float*)d_in[0];
    const float* W1 = (const float*)d_in[1];
    const float* B1 = (const float*)d_in[2];
    const float* W2 = (const float*)d_in[3];
    const float* B2 = (const float*)d_in[4];
    const float* W3 = (const float*)d_in[5];
    float* OUT = (float*)d_out;
    int blocks = in_sizes[0] / 512;   // 64 batch rows per block
    hipLaunchKernelGGL(hnn_kernel, dim3(blocks), dim3(256), 0, stream,
                       Z, W1, B1, W2, B2, W3, OUT);
}

// Round 4
// 860.948 us; speedup vs baseline: 1.0050x; 1.0050x over previous
//
#include <hip/hip_runtime.h>

// SymplecticLayer: 2 leapfrog steps, force = grad of tanh-MLP Hamiltonian (8->128->128->1).
// Round 4: Round 3 algorithm unchanged. Single fix: amdgpu_waves_per_eu(4,4).
// R2/R3 spilled all 48 dwords of loop-carried state (u/pk/bf) because the
// allocator targeted 8 waves/EU (64-VGPR budget) -- pointless, since LDS caps
// occupancy at 4 waves/EU. Pinning min=max=4 gives a 128-VGPR budget -> no spill.

typedef float f32x4 __attribute__((ext_vector_type(4)));

#define DT   0.01f
#define L2E2 2.8853901f   // 2*log2(e)

__device__ __forceinline__ int bperm(int idx, int v) {
    return __builtin_amdgcn_ds_bpermute(idx, v);
}
__device__ __forceinline__ int pack4(float a, float b, float c, float d) {
    int v = __builtin_amdgcn_cvt_pk_fp8_f32(a, b, 0, false);
    v = __builtin_amdgcn_cvt_pk_fp8_f32(c, d, v, true);
    return v;
}
__device__ __forceinline__ unsigned char to_fp8(float x) {
    return (unsigned char)(__builtin_amdgcn_cvt_pk_fp8_f32(x, x, 0, false) & 0xff);
}
__device__ __forceinline__ f32x4 mfma8(long long a, long long b, f32x4 c) {
    return __builtin_amdgcn_mfma_f32_16x16x32_fp8_fp8(a, b, c, 0, 0, 0);
}

// one B-frag dword-pair from two C-layout packed dwords (conflict-free crossbar)
#define XF(PKA, PKB, BF) {                                      \
    int la_ = bperm(idx_lo, (PKA));                             \
    int lb_ = bperm(idx_lo, (PKB));                             \
    int ha_ = bperm(idx_hi, (PKA));                             \
    int hb_ = bperm(idx_hi, (PKB));                             \
    int lo_ = sel ? la_ : lb_;                                  \
    int hi_ = sel ? ha_ : hb_;                                  \
    (BF) = (((long long)(unsigned)hi_) << 32) | (unsigned)lo_;  \
}
#define XFORM4() { XF(pk0,pk1,bf0); XF(pk2,pk3,bf1); XF(pk4,pk5,bf2); XF(pk6,pk7,bf3); }

#define TANHU(X, H, U) {                                        \
    float e_  = __builtin_amdgcn_exp2f((X) * L2E2);             \
    float rc_ = __builtin_amdgcn_rcpf(1.0f + e_);               \
    (H) = 1.0f - 2.0f * rc_;                                    \
    (U) = __builtin_fmaf(-(H), (H), 1.0f);                      \
}

// L1 fwd tile NT: h1 = tanh(z@W1+b1) -> PK (packed fp8), UV (1-h1^2)
#define L1FWD(NT, PK, UV) {                                                    \
    long long a_ = *(const long long*)(sW1A + (NT) * 512 + laneB);             \
    f32x4 acc_ = mfma8(a_, zB, (f32x4){0.f, 0.f, 0.f, 0.f});                   \
    float hA_, hB_, hC_, hD_;                                                  \
    TANHU(acc_[0], hA_, (UV)[0]); TANHU(acc_[1], hB_, (UV)[1]);                \
    TANHU(acc_[2], hC_, (UV)[2]); TANHU(acc_[3], hD_, (UV)[3]);                \
    (PK) = pack4(hA_, hB_, hC_, hD_);                                          \
}

// L2 fwd tile NT: d2' = 16*sech^2(h1@W2+b2) -> PK
#define L2FWD(NT, PK) {                                                        \
    f32x4 b2c_ = *(const f32x4*)(sB2 + (NT) * 16 + qd * 4);                    \
    f32x4 acc_ = {0.f, 0.f, 0.f, 0.f};                                         \
    acc_ = mfma8(*(const long long*)(sW2F + ((NT)*4+0)*512 + laneB), bf0, acc_); \
    acc_ = mfma8(*(const long long*)(sW2F + ((NT)*4+1)*512 + laneB), bf1, acc_); \
    acc_ = mfma8(*(const long long*)(sW2F + ((NT)*4+2)*512 + laneB), bf2, acc_); \
    acc_ = mfma8(*(const long long*)(sW2F + ((NT)*4+3)*512 + laneB), bf3, acc_); \
    float dA_, dB_, dC_, dD_;                                                  \
    D2OF(acc_[0], b2c_[0], dA_); D2OF(acc_[1], b2c_[1], dB_);                  \
    D2OF(acc_[2], b2c_[2], dC_); D2OF(acc_[3], b2c_[3], dD_);                  \
    (PK) = pack4(dA_, dB_, dC_, dD_);                                          \
}
#define D2OF(ACC, B2C, D) {                                                    \
    float arg_ = __builtin_fmaf((ACC), 0.36067376f, (B2C));                    \
    arg_ = fminf(arg_, 126.0f);                                                \
    float e_  = __builtin_amdgcn_exp2f(arg_);                                  \
    float rc_ = __builtin_amdgcn_rcpf(1.0f + e_);                              \
    (D) = 64.0f * (e_ * rc_) * rc_;                                            \
}

// L2 bwd tile NT: d1 = u .* (d2' @ w3W2^T) * (1/32) -> PK
#define L2BWD(NT, PK, UV) {                                                    \
    f32x4 acc_ = {0.f, 0.f, 0.f, 0.f};                                         \
    acc_ = mfma8(*(const long long*)(sW2R + ((NT)*4+0)*512 + laneB), bf0, acc_); \
    acc_ = mfma8(*(const long long*)(sW2R + ((NT)*4+1)*512 + laneB), bf1, acc_); \
    acc_ = mfma8(*(const long long*)(sW2R + ((NT)*4+2)*512 + laneB), bf2, acc_); \
    acc_ = mfma8(*(const long long*)(sW2R + ((NT)*4+3)*512 + laneB), bf3, acc_); \
    (PK) = pack4((acc_[0] * (UV)[0]) * 0.03125f, (acc_[1] * (UV)[1]) * 0.03125f, \
                 (acc_[2] * (UV)[2]) * 0.03125f, (acc_[3] * (UV)[3]) * 0.03125f); \
}

__global__ __launch_bounds__(256)
__attribute__((amdgpu_waves_per_eu(4, 4)))
void hnn_kernel(
    const float* __restrict__ Z, const float* __restrict__ W1,
    const float* __restrict__ B1, const float* __restrict__ W2,
    const float* __restrict__ B2, const float* __restrict__ W3,
    float* __restrict__ OUT)
{
    // ---- LDS: 4096+16384+16384+2048+512 = 39,424 B -> 4 blocks/CU ----
    __shared__ __align__(16) unsigned char sW1A[4096];    // fwd A = W1^T (m=f, k=i; k=8 -> b1)
    __shared__ __align__(16) unsigned char sW2F[16384];   // fwd A = 8*W2^T (m=k2, k=j)
    __shared__ __align__(16) unsigned char sW2R[16384];   // bwd A = 128*w3(.)W2 (m=j, k=k2)
    __shared__ __align__(16) unsigned char sW1R[2048];    // bwd A = W1 (m=i pad16, k=f)
    __shared__ __align__(16) float sB2[128];              // b2 * 2log2e

    const int t = threadIdx.x, blk = blockIdx.x;

    for (int i = t; i < 1024; i += 256) ((int*)sW1A)[i] = 0;
    for (int i = t; i < 512;  i += 256) ((int*)sW1R)[i] = 0;
    __syncthreads();

    // W1 (8x128, row-major [i][f])
    for (int i = t; i < 1024; i += 256) {
        int i8 = i >> 7, f = i & 127;
        unsigned char q = to_fp8(W1[i]);
        sW1A[(f >> 4) * 512 + (f & 15) * 8 + i8] = q;
        sW1R[(f >> 5) * 512 + (i8 | (((f >> 3) & 3) << 4)) * 8 + (f & 7)] = q;
    }
    if (t < 128) {
        sW1A[(t >> 4) * 512 + ((t & 15) + 16) * 8] = to_fp8(B1[t]);  // bias row k=8
        sB2[t] = B2[t] * L2E2;
    }
    // W2 (128x128, row-major [j][k2])
    for (int i = t; i < 4096; i += 256) {
        f32x4 w  = ((const f32x4*)W2)[i];
        f32x4 w3 = *(const f32x4*)(W3 + ((i * 4) & 127));
        int j = (i * 4) >> 7, k0 = (i * 4) & 127;
        #pragma unroll
        for (int u = 0; u < 4; u++) {
            int k2 = k0 + u;
            sW2F[(((k2 >> 4) << 2) | (j >> 5)) * 512
                 + ((k2 & 15) | (((j >> 3) & 3) << 4)) * 8 + (j & 7)] = to_fp8(w[u] * 8.0f);
            sW2R[(((j >> 4) << 2) | (k2 >> 5)) * 512
                 + ((j & 15) | (((k2 >> 3) & 3) << 4)) * 8 + (k2 & 7)] = to_fp8(w[u] * w3[u] * 128.0f);
        }
    }
    __syncthreads();
    // No further barriers: everything below is wave-local.

    const int lane = t & 63, wv = t >> 6;
    const int c = lane & 15, qd = lane >> 4;
    const int laneB = lane * 8;
    const bool sel = qd < 2;
    const int idx_pt = (lane ^ 16) << 2;
    const int idx_lo = ((((2 * qd) & 3) << 4) | c) << 2;
    const int idx_hi = (((((2 * qd) | 1) & 3) << 4) | c) << 2;
    const int row = blk * 64 + wv * 16 + c;
    const float cp  = (qd == 0) ? (-0.5f * DT / 64.0f) : 0.0f;  // p -= 0.5*DT*dHdq (acc scale 64)
    const float cqb = (qd == 1) ? (DT / 64.0f) : 0.0f;          // q += DT*dHdp (even evs)

    // state: qd0/2 lanes hold p[c][0..3], qd1/3 lanes hold q[c][0..3]
    f32x4 st = *(const f32x4*)(Z + row * 8 + ((qd & 1) ? 0 : 4));

    f32x4 u0, u1, u2, u3, u4, u5, u6, u7;     // 1 - h1^2, C-layout
    int pk0, pk1, pk2, pk3, pk4, pk5, pk6, pk7;
    long long bf0, bf1, bf2, bf3;

    #pragma unroll 1
    for (int ev = 0; ev < 4; ev++) {
        // ---- build z B-frag: k=0..7 = (q,p), k=8 = 1.0 (bias row) ----
        int own = pack4(st[0], st[1], st[2], st[3]);
        int oth = bperm(idx_pt, own);
        int zlo = (qd == 0) ? oth : ((qd == 1) ? 0x38 : 0);   // 0x38 = e4m3(1.0)
        int zhi = (qd == 0) ? own : 0;
        long long zB = (((long long)(unsigned)zhi) << 32) | (unsigned)zlo;

        L1FWD(0, pk0, u0); L1FWD(1, pk1, u1); L1FWD(2, pk2, u2); L1FWD(3, pk3, u3);
        L1FWD(4, pk4, u4); L1FWD(5, pk5, u5); L1FWD(6, pk6, u6); L1FWD(7, pk7, u7);
        XFORM4();

        L2FWD(0, pk0); L2FWD(1, pk1); L2FWD(2, pk2); L2FWD(3, pk3);
        L2FWD(4, pk4); L2FWD(5, pk5); L2FWD(6, pk6); L2FWD(7, pk7);
        XFORM4();

        L2BWD(0, pk0, u0); L2BWD(1, pk1, u1); L2BWD(2, pk2, u2); L2BWD(3, pk3, u3);
        L2BWD(4, pk4, u4); L2BWD(5, pk5, u5); L2BWD(6, pk6, u6); L2BWD(7, pk7, u7);
        XFORM4();

        // ---- L1 bwd: g = d1 @ W1^T (m=0..3 dHdq -> qd0, m=4..7 dHdp -> qd1) ----
        f32x4 g = {0.f, 0.f, 0.f, 0.f};
        g = mfma8(*(const long long*)(sW1R + 0 * 512 + laneB), bf0, g);
        g = mfma8(*(const long long*)(sW1R + 1 * 512 + laneB), bf1, g);
        g = mfma8(*(const long long*)(sW1R + 2 * 512 + laneB), bf2, g);
        g = mfma8(*(const long long*)(sW1R + 3 * 512 + laneB), bf3, g);

        float coef = cp + ((ev & 1) ? 0.0f : cqb);
        st[0] = __builtin_fmaf(coef, g[0], st[0]);
        st[1] = __builtin_fmaf(coef, g[1], st[1]);
        st[2] = __builtin_fmaf(coef, g[2], st[2]);
        st[3] = __builtin_fmaf(coef, g[3], st[3]);
    }

    if (qd < 2) *(f32x4*)(OUT + row * 8 + ((qd & 1) ? 0 : 4)) = st;
}

extern "C" void kernel_launch(void* const* d_in, const int* in_sizes, int n_in,
                              void* d_out, int out_size, void* d_ws, size_t ws_size,
                              hipStream_t stream) {
    const float* Z  = (const float*)d_in[0];
    const float* W1 = (const float*)d_in[1];
    const float* B1 = (const float*)d_in[2];
    const float* W2 = (const float*)d_in[3];
    const float* B2 = (const float*)d_in[4];
    const float* W3 = (const float*)d_in[5];
    float* OUT = (float*)d_out;
    int blocks = in_sizes[0] / 512;   // 64 batch rows per block
    hipLaunchKernelGGL(hnn_kernel, dim3(blocks), dim3(256), 0, stream,
                       Z, W1, B1, W2, B2, W3, OUT);
}